// Round 1
// baseline (4230.135 us; speedup 1.0000x reference)
//
#include <hip/hip_runtime.h>
#include <hip/hip_bf16.h>
#include <math.h>

typedef __hip_bfloat16 bf16;

#define DEV __device__ __forceinline__

DEV float to_f(float v){ return v; }
DEV float to_f(bf16 v){ return __bfloat162float(v); }
DEV bf16 f2b(float v){ return __float2bfloat16(v); }

DEV float gelu_f(float x){
  float x3 = x*x*x;
  return 0.5f*x*(1.0f + tanhf(0.7978845608028654f*(x + 0.044715f*x3)));
}

// ---------------- encoder Conv_trio: conv(3x3,stride) + channel-norm + gelu ----
// Thread handles one pixel's CO_PER=COUT/SUB channels; SUB lanes per pixel.
template<typename TIN, int CIN, int COUT, int SUB, int STRIDE, int HI, int WI>
__global__ void trio_kernel(const TIN* __restrict__ in, const float* __restrict__ w,
                            const float* __restrict__ bias, bf16* __restrict__ out){
  constexpr int HO = HI/STRIDE, WO = WI/STRIDE;
  constexpr int CO_PER = COUT/SUB;
  int gtid = blockIdx.x*blockDim.x + threadIdx.x;
  int sub = gtid % SUB;
  int pix = gtid / SUB;
  int b = pix / (HO*WO); int rem = pix % (HO*WO);
  int y = rem / WO, x = rem % WO;

  float acc[CO_PER];
  #pragma unroll
  for (int j=0;j<CO_PER;j++) acc[j]=0.f;

  for (int ky=0;ky<3;ky++){
    int iy = (STRIDE==1) ? (y+ky-1) : (2*y+ky);
    if (iy<0 || iy>=HI) continue;
    for (int kx=0;kx<3;kx++){
      int ix = (STRIDE==1) ? (x+kx-1) : (2*x+kx);
      if (ix<0 || ix>=WI) continue;
      const TIN* ip = in + ((size_t)(b*HI+iy)*WI+ix)*CIN;
      const float* wp = w + ((ky*3+kx)*CIN)*COUT + sub*CO_PER;
      #pragma unroll 4
      for (int ci=0; ci<CIN; ci++){
        float a = to_f(ip[ci]);
        const float4* w4 = (const float4*)(wp + (size_t)ci*COUT);
        #pragma unroll
        for (int j=0;j<CO_PER/4;j++){
          float4 ww = w4[j];
          acc[4*j+0] += a*ww.x; acc[4*j+1] += a*ww.y;
          acc[4*j+2] += a*ww.z; acc[4*j+3] += a*ww.w;
        }
      }
    }
  }

  float s1=0.f, s2=0.f;
  #pragma unroll
  for (int j=0;j<CO_PER;j++){
    acc[j] += bias[sub*CO_PER+j];
    s1 += acc[j]; s2 += acc[j]*acc[j];
  }
  if (SUB>=2){ s1 += __shfl_xor(s1,1,64); s2 += __shfl_xor(s2,1,64); }
  if (SUB>=4){ s1 += __shfl_xor(s1,2,64); s2 += __shfl_xor(s2,2,64); }
  float mu  = s1*(1.0f/COUT);
  float var = s2*(1.0f/COUT) - mu*mu;
  float sc  = rsqrtf(var + 1e-6f);

  bf16* op = out + (size_t)pix*COUT + sub*CO_PER;
  #pragma unroll
  for (int j=0;j<CO_PER;j++) op[j] = f2b(gelu_f((acc[j]-mu)*sc));
}

// ---------------- conv_transpose(3x3, stride 2 along DIM) + bias + gelu --------
// SAME padding for k=3,s=2 -> dilated-input pad (2,1):
//   even o: taps k=0 @ (o-2)/2 (if o>=2), k=2 @ o/2 ; odd o: k=1 @ (o-1)/2
// non-strided dim: standard 3-tap correlation pad (1,1). Kernel NOT flipped.
template<int DIM, int HI, int WI>
__global__ void upconv_kernel(const bf16* __restrict__ in, const float* __restrict__ w,
                              const float* __restrict__ bias, bf16* __restrict__ out){
  constexpr int HO = (DIM==0)? HI*2 : HI;
  constexpr int WO = (DIM==0)? WI : WI*2;
  int gtid = blockIdx.x*blockDim.x + threadIdx.x;
  int cg = gtid & 15; int pix = gtid >> 4;
  int b = pix / (HO*WO); int rem = pix % (HO*WO);
  int y = rem / WO, x = rem % WO;
  int co0 = cg*4;

  int kys[3], iys[3], nky=0;
  if (DIM==0){
    if ((y&1)==0){
      if (y>=2){ kys[nky]=0; iys[nky]=(y-2)>>1; nky++; }
      kys[nky]=2; iys[nky]=y>>1; nky++;
    } else { kys[0]=1; iys[0]=(y-1)>>1; nky=1; }
  } else {
    for (int k=0;k<3;k++){ int iy=y+k-1; if(iy>=0&&iy<HI){kys[nky]=k; iys[nky]=iy; nky++;} }
  }
  int kxs[3], ixs[3], nkx=0;
  if (DIM==1){
    if ((x&1)==0){
      if (x>=2){ kxs[nkx]=0; ixs[nkx]=(x-2)>>1; nkx++; }
      kxs[nkx]=2; ixs[nkx]=x>>1; nkx++;
    } else { kxs[0]=1; ixs[0]=(x-1)>>1; nkx=1; }
  } else {
    for (int k=0;k<3;k++){ int ix=x+k-1; if(ix>=0&&ix<WI){kxs[nkx]=k; ixs[nkx]=ix; nkx++;} }
  }

  float4 acc = *(const float4*)(bias + co0);
  for (int a=0;a<nky;a++){
    for (int c=0;c<nkx;c++){
      const bf16* ip = in + ((size_t)(b*HI+iys[a])*WI + ixs[c])*64;
      const float* wp = w + ((size_t)(kys[a]*3+kxs[c])*64)*64 + co0;
      #pragma unroll 8
      for (int ci=0;ci<64;ci++){
        float v = to_f(ip[ci]);
        float4 ww = *(const float4*)(wp + (size_t)ci*64);
        acc.x += v*ww.x; acc.y += v*ww.y; acc.z += v*ww.z; acc.w += v*ww.w;
      }
    }
  }
  bf16* op = out + (size_t)pix*64 + co0;
  op[0]=f2b(gelu_f(acc.x)); op[1]=f2b(gelu_f(acc.y));
  op[2]=f2b(gelu_f(acc.z)); op[3]=f2b(gelu_f(acc.w));
}

// ---------------- mask conv + softmax + mask update + loss terms ---------------
template<int STEP, int DIM, int HH, int WW>
__global__ void maskloss_kernel(const bf16* __restrict__ feat, const float* __restrict__ mw,
                                const float* __restrict__ mb, const float* __restrict__ img,
                                const float* __restrict__ masks_in, float* __restrict__ masks_out,
                                float* __restrict__ acc){
  int idx = blockIdx.x*blockDim.x + threadIdx.x;
  int b = idx / (HH*WW); int rem = idx % (HH*WW);
  int y = rem / WW, x = rem % WW;

  float l0=mb[0], l1=mb[1], l2=mb[2], l3=mb[3];
  for (int ky=0;ky<3;ky++){ int yy=y+ky-1; if(yy<0||yy>=HH) continue;
    for (int kx=0;kx<3;kx++){ int xx=x+kx-1; if(xx<0||xx>=WW) continue;
      const bf16* ip = feat + ((size_t)(b*HH+yy)*WW+xx)*64;
      const float* wp = mw + (size_t)(ky*3+kx)*64*4;
      #pragma unroll 8
      for (int ci=0;ci<64;ci++){
        float v = to_f(ip[ci]);
        float4 ww = *(const float4*)(wp + ci*4);
        l0 += v*ww.x; l1 += v*ww.y; l2 += v*ww.z; l3 += v*ww.w;
      }
    }
  }
  float m = fmaxf(fmaxf(l0,l1),fmaxf(l2,l3));
  float e0=expf(l0-m), e1=expf(l1-m), e2=expf(l2-m), e3=expf(l3-m);
  float inv = 1.0f/(e0+e1+e2+e3);
  float p0=e0*inv, p1=e1*inv, p2=e2*inv, p3=e3*inv;
  float sval = p1 + 2.f*p2 + 3.f*p3;

  constexpr int HM = (DIM==0)? HH/2 : HH;
  constexpr int WM = (DIM==0)? WW : WW/2;
  int my = (DIM==0)? (y>>1) : y;
  int mx = (DIM==1)? (x>>1) : x;
  float mv = masks_in[((size_t)b*HM+my)*WM+mx];
  masks_out[idx] = mv + 0.25f*sval;

  float ent = -(p0*logf(p0+1e-8f)+p1*logf(p1+1e-8f)+p2*logf(p2+1e-8f)+p3*logf(p3+1e-8f));

  constexpr int FH = 256/HH, FW = 256/WW;
  float isum=0.f;
  const float* ib = img + ((size_t)b*256 + y*FH)*256 + x*FW;
  for (int dy=0;dy<FH;dy++)
    for (int dx=0;dx<FW;dx++) isum += ib[dy*256+dx];
  float img_ds = isum * (1.0f/(FH*FW));
  float d = sval*(1.0f/3.0f) - img_ds;
  float mse = d*d;

  #pragma unroll
  for (int off=1; off<64; off<<=1){
    ent += __shfl_xor(ent, off, 64);
    mse += __shfl_xor(mse, off, 64);
  }
  if ((threadIdx.x & 63)==0){
    atomicAdd(acc+2*STEP,   ent);
    atomicAdd(acc+2*STEP+1, mse);
  }
}

__global__ void finalize_kernel(const float* __restrict__ acc, float* __restrict__ out){
  const float lw[6] = {0.1f,0.1f,0.5f,0.5f,1.0f,1.0f};
  const float nn[6] = {16384.f,32768.f,65536.f,131072.f,262144.f,524288.f};
  float L=0.f;
  for (int i=0;i<6;i++) L += lw[i]*(acc[2*i]/nn[i] + acc[2*i+1]/nn[i]);
  out[0]=L;
}

extern "C" void kernel_launch(void* const* d_in, const int* in_sizes, int n_in,
                              void* d_out, int out_size, void* d_ws, size_t ws_size,
                              hipStream_t stream){
  const float* image  = (const float*)d_in[0];
  const float* w1=(const float*)d_in[2];  const float* b1=(const float*)d_in[3];
  const float* w2=(const float*)d_in[4];  const float* b2=(const float*)d_in[5];
  const float* w3=(const float*)d_in[6];  const float* b3=(const float*)d_in[7];
  const float* w4=(const float*)d_in[8];  const float* b4=(const float*)d_in[9];
  const float* upw=(const float*)d_in[10];const float* upb=(const float*)d_in[11];
  const float* mw=(const float*)d_in[12]; const float* mb=(const float*)d_in[13];
  const float* masks0=(const float*)d_in[14];
  float* out = (float*)d_out;

  char* ws = (char*)d_ws;
  size_t off = 0;
  auto alloc = [&](size_t bytes)->char*{
    char* p = ws + off; off += (bytes + 255) & ~(size_t)255; return p;
  };
  bf16* enc1  = (bf16*)alloc((size_t)8*256*256*16*2);
  bf16* enc2  = (bf16*)alloc((size_t)8*128*128*16*2);
  bf16* enc3  = (bf16*)alloc((size_t)8*64*64*32*2);
  bf16* featA = (bf16*)alloc((size_t)8*256*256*64*2);
  bf16* featB = (bf16*)alloc((size_t)8*256*128*64*2);
  float* mbA  = (float*)alloc((size_t)8*256*128*4);
  float* mbB  = (float*)alloc((size_t)8*128*128*4);
  float* acc  = (float*)alloc(256);

  hipMemsetAsync(acc, 0, 12*sizeof(float), stream);

  // encoder
  trio_kernel<float,1,16,1,1,256,256><<<8*256*256/256,256,0,stream>>>(image,w1,b1,enc1);
  trio_kernel<bf16,16,16,1,2,256,256><<<8*128*128/256,256,0,stream>>>(enc1,w2,b2,enc2);
  trio_kernel<bf16,16,32,2,2,128,128><<<8*64*64*2/256,256,0,stream>>>(enc2,w3,b3,enc3);
  trio_kernel<bf16,32,64,4,2,64,64><<<8*32*32*4/256,256,0,stream>>>(enc3,w4,b4,featA);

  // step 0: (32,32) -> (64,32)
  upconv_kernel<0,32,32><<<8*64*32*16/256,256,0,stream>>>(featA,upw,upb,featB);
  maskloss_kernel<0,0,64,32><<<8*64*32/256,256,0,stream>>>(featB,mw,mb,image,masks0,mbA,acc);
  // step 1: (64,32) -> (64,64)
  upconv_kernel<1,64,32><<<8*64*64*16/256,256,0,stream>>>(featB,upw,upb,featA);
  maskloss_kernel<1,1,64,64><<<8*64*64/256,256,0,stream>>>(featA,mw,mb,image,mbA,mbB,acc);
  // step 2: (64,64) -> (128,64)
  upconv_kernel<0,64,64><<<8*128*64*16/256,256,0,stream>>>(featA,upw,upb,featB);
  maskloss_kernel<2,0,128,64><<<8*128*64/256,256,0,stream>>>(featB,mw,mb,image,mbB,mbA,acc);
  // step 3: (128,64) -> (128,128)
  upconv_kernel<1,128,64><<<8*128*128*16/256,256,0,stream>>>(featB,upw,upb,featA);
  maskloss_kernel<3,1,128,128><<<8*128*128/256,256,0,stream>>>(featA,mw,mb,image,mbA,mbB,acc);
  // step 4: (128,128) -> (256,128)
  upconv_kernel<0,128,128><<<8*256*128*16/256,256,0,stream>>>(featA,upw,upb,featB);
  maskloss_kernel<4,0,256,128><<<8*256*128/256,256,0,stream>>>(featB,mw,mb,image,mbB,mbA,acc);
  // step 5: (128,128)x(256,128) -> (256,256)
  upconv_kernel<1,256,128><<<8*256*256*16/256,256,0,stream>>>(featB,upw,upb,featA);
  maskloss_kernel<5,1,256,256><<<8*256*256/256,256,0,stream>>>(featA,mw,mb,image,mbA,out+1,acc);

  finalize_kernel<<<1,1,0,stream>>>(acc,out);
}

// Round 2
// 2129.143 us; speedup vs baseline: 1.9868x; 1.9868x over previous
//
#include <hip/hip_runtime.h>
#include <hip/hip_bf16.h>
#include <math.h>

typedef __hip_bfloat16 bf16;
typedef float f32x4 __attribute__((ext_vector_type(4)));
typedef __bf16 bf16x8 __attribute__((ext_vector_type(8)));

#define DEV __device__ __forceinline__

DEV float to_f(float v){ return v; }
DEV float to_f(bf16 v){ return __bfloat162float(v); }
DEV bf16 f2b(float v){ return __float2bfloat16(v); }

// tanh-approx gelu == x * sigmoid(2*0.79788456*(x+0.044715x^3)); hw exp
DEV float gelu_f(float x){
  float z = 1.5957691216057308f*(x + 0.044715f*x*x*x);
  return x / (1.0f + __expf(-z));
}

DEV bf16x8 load_frag(const bf16* p, bool ok){
  uint4 u = make_uint4(0u,0u,0u,0u);
  if (ok) u = *(const uint4*)p;
  return __builtin_bit_cast(bf16x8, u);
}

// ---------------- encoder Conv_trio (unchanged from round 1) ------------------
template<typename TIN, int CIN, int COUT, int SUB, int STRIDE, int HI, int WI>
__global__ void trio_kernel(const TIN* __restrict__ in, const float* __restrict__ w,
                            const float* __restrict__ bias, bf16* __restrict__ out){
  constexpr int HO = HI/STRIDE, WO = WI/STRIDE;
  constexpr int CO_PER = COUT/SUB;
  int gtid = blockIdx.x*blockDim.x + threadIdx.x;
  int sub = gtid % SUB;
  int pix = gtid / SUB;
  int b = pix / (HO*WO); int rem = pix % (HO*WO);
  int y = rem / WO, x = rem % WO;

  float acc[CO_PER];
  #pragma unroll
  for (int j=0;j<CO_PER;j++) acc[j]=0.f;

  for (int ky=0;ky<3;ky++){
    int iy = (STRIDE==1) ? (y+ky-1) : (2*y+ky);
    if (iy<0 || iy>=HI) continue;
    for (int kx=0;kx<3;kx++){
      int ix = (STRIDE==1) ? (x+kx-1) : (2*x+kx);
      if (ix<0 || ix>=WI) continue;
      const TIN* ip = in + ((size_t)(b*HI+iy)*WI+ix)*CIN;
      const float* wp = w + ((ky*3+kx)*CIN)*COUT + sub*CO_PER;
      #pragma unroll 4
      for (int ci=0; ci<CIN; ci++){
        float a = to_f(ip[ci]);
        const float4* w4 = (const float4*)(wp + (size_t)ci*COUT);
        #pragma unroll
        for (int j=0;j<CO_PER/4;j++){
          float4 ww = w4[j];
          acc[4*j+0] += a*ww.x; acc[4*j+1] += a*ww.y;
          acc[4*j+2] += a*ww.z; acc[4*j+3] += a*ww.w;
        }
      }
    }
  }

  float s1=0.f, s2=0.f;
  #pragma unroll
  for (int j=0;j<CO_PER;j++){
    acc[j] += bias[sub*CO_PER+j];
    s1 += acc[j]; s2 += acc[j]*acc[j];
  }
  if (SUB>=2){ s1 += __shfl_xor(s1,1,64); s2 += __shfl_xor(s2,1,64); }
  if (SUB>=4){ s1 += __shfl_xor(s1,2,64); s2 += __shfl_xor(s2,2,64); }
  float mu  = s1*(1.0f/COUT);
  float var = s2*(1.0f/COUT) - mu*mu;
  float sc  = rsqrtf(var + 1e-6f);

  bf16* op = out + (size_t)pix*COUT + sub*CO_PER;
  #pragma unroll
  for (int j=0;j<CO_PER;j++) op[j] = f2b(gelu_f((acc[j]-mu)*sc));
}

// ---------------- weight repack for MFMA B fragments ---------------------------
// B[k=quad*8+j][n=lane&15]; packed idx v = (((tap*2+c)*4+nt)*64+lane)*8+j
__global__ void repack_up(const float* __restrict__ w, bf16* __restrict__ bp){
  int v = blockIdx.x*256 + threadIdx.x;
  if (v >= 9*2*4*64*8) return;
  int j = v & 7; int lane = (v>>3)&63; int nt = (v>>9)&3; int c = (v>>11)&1; int tap = v>>12;
  int ci = c*32 + (lane>>4)*8 + j;
  int co = nt*16 + (lane&15);
  bp[v] = f2b(w[(tap*64+ci)*64 + co]);
}

// mask conv B: only one ntile; cols 4..15 zero. v = ((tap*2+c)*64+lane)*8+j
__global__ void repack_mask(const float* __restrict__ w, bf16* __restrict__ bp){
  int v = blockIdx.x*256 + threadIdx.x;
  if (v >= 9*2*64*8) return;
  int j = v & 7; int lane = (v>>3)&63; int c = (v>>9)&1; int tap = v>>10;
  int ci = c*32 + (lane>>4)*8 + j;
  int n = lane & 15;
  bp[v] = (n < 4) ? f2b(w[(tap*64+ci)*4 + n]) : f2b(0.0f);
}

// ---------------- MFMA conv_transpose(3x3, stride 2 along DIM) + gelu ----------
// Even strided outputs o=2q: taps k=0 @ q-1, k=2 @ q. Odd o=2q+1: k=1 @ q.
// One wave computes 16 parity-pure pixels x 64 cout.
template<int DIM, int HI, int WI>
__global__ void upconv_mfma(const bf16* __restrict__ in, const bf16* __restrict__ bpack,
                            const float* __restrict__ upb, bf16* __restrict__ out){
  constexpr int HO = (DIM==0)? HI*2 : HI;
  constexpr int WO = (DIM==0)? WI : WI*2;
  constexpr int U  = (DIM==0)? WI : HI;     // input extent along non-strided dim
  int lane = threadIdx.x & 63;
  int wv   = threadIdx.x >> 6;
  int wtile = blockIdx.x*4 + wv;
  int m = lane & 15, quad = lane >> 4;

  int b, y0=0, x0=0, o, u;
  if (DIM==0){
    constexpr int TPR = WO/16;
    x0 = (wtile % TPR)*16;
    int y = (wtile / TPR) % HO;
    b = wtile / (TPR*HO);
    y0 = y;            // uniform strided coord
    o = y; u = x0 + m;
  } else {
    int x = wtile % WO;
    y0 = ((wtile / WO) % (HO/16))*16;
    b = wtile / (WO*(HO/16));
    x0 = x;
    o = x; u = y0 + m;
  }

  int q = o >> 1;
  int stk[2], stq[2]; int nst;
  if (o & 1){ stk[0]=1; stq[0]=q; nst=1; }
  else {
    nst = 0;
    if (q >= 1){ stk[0]=0; stq[0]=q-1; nst=1; }
    stk[nst]=2; stq[nst]=q; nst++;
  }

  f32x4 acc[4];
  #pragma unroll
  for (int nt=0;nt<4;nt++) acc[nt] = (f32x4){0.f,0.f,0.f,0.f};

  const uint4* bp4 = (const uint4*)bpack;

  for (int s=0; s<nst; s++){
    #pragma unroll
    for (int ut=0; ut<3; ut++){
      int uu = u - 1 + ut;
      bool ok = (uu >= 0) && (uu < U);
      int iy = (DIM==0)? stq[s] : uu;
      int ix = (DIM==0)? uu : stq[s];
      int tap = (DIM==0)? stk[s]*3+ut : ut*3+stk[s];
      const bf16* ip = in + (((size_t)(b*HI+iy)*WI + ix)*64 + quad*8);
      #pragma unroll
      for (int c=0;c<2;c++){
        bf16x8 a = load_frag(ip + c*32, ok);
        #pragma unroll
        for (int nt=0;nt<4;nt++){
          uint4 ub = bp4[((tap*2+c)*4+nt)*64 + lane];
          bf16x8 bb = __builtin_bit_cast(bf16x8, ub);
          acc[nt] = __builtin_amdgcn_mfma_f32_16x16x32_bf16(a, bb, acc[nt], 0, 0, 0);
        }
      }
    }
  }

  // epilogue: D[row=quad*4+r][col=lane&15]
  int col = m;
  #pragma unroll
  for (int nt=0;nt<4;nt++){
    float bv = upb[nt*16 + col];
    #pragma unroll
    for (int r=0;r<4;r++){
      int p = quad*4 + r;
      size_t opix = (DIM==0) ? (((size_t)b*HO + y0)*WO + x0 + p)
                             : (((size_t)b*HO + y0 + p)*WO + x0);
      out[opix*64 + nt*16 + col] = f2b(gelu_f(acc[nt][r] + bv));
    }
  }
}

// ---------------- MFMA mask conv + softmax + mask update + loss ----------------
template<int STEP, int DIM, int HH, int WW>
__global__ void maskloss_mfma(const bf16* __restrict__ feat, const bf16* __restrict__ mpack,
                              const float* __restrict__ mb, const float* __restrict__ img,
                              const float* __restrict__ masks_in, float* __restrict__ masks_out,
                              float* __restrict__ accbuf){
  __shared__ float llog[4][16][4];
  int lane = threadIdx.x & 63;
  int wv   = threadIdx.x >> 6;
  int wtile = blockIdx.x*4 + wv;
  int m = lane & 15, quad = lane >> 4;

  constexpr int TPR = WW/16;
  int x0 = (wtile % TPR)*16;
  int y  = (wtile / TPR) % HH;
  int b  = wtile / (TPR*HH);

  f32x4 acc4 = (f32x4){0.f,0.f,0.f,0.f};
  const uint4* bp4 = (const uint4*)mpack;

  for (int ky=0; ky<3; ky++){
    int iy = y + ky - 1;
    if (iy < 0 || iy >= HH) continue;
    #pragma unroll
    for (int kx=0; kx<3; kx++){
      int ix = x0 + m + kx - 1;
      bool ok = (ix >= 0) && (ix < WW);
      int tap = ky*3 + kx;
      const bf16* ip = feat + (((size_t)(b*HH+iy)*WW + ix)*64 + quad*8);
      #pragma unroll
      for (int c=0;c<2;c++){
        bf16x8 a = load_frag(ip + c*32, ok);
        uint4 ub = bp4[(tap*2+c)*64 + lane];
        bf16x8 bb = __builtin_bit_cast(bf16x8, ub);
        acc4 = __builtin_amdgcn_mfma_f32_16x16x32_bf16(a, bb, acc4, 0, 0, 0);
      }
    }
  }

  int col = m;
  if (col < 4){
    #pragma unroll
    for (int r=0;r<4;r++) llog[wv][quad*4+r][col] = acc4[r] + mb[col];
  }
  __syncthreads();

  float ent = 0.f, mse = 0.f;
  if (lane < 16){
    int p = lane; int xx = x0 + p;
    float l0 = llog[wv][p][0], l1 = llog[wv][p][1];
    float l2 = llog[wv][p][2], l3 = llog[wv][p][3];
    float mx = fmaxf(fmaxf(l0,l1), fmaxf(l2,l3));
    float e0=__expf(l0-mx), e1=__expf(l1-mx), e2=__expf(l2-mx), e3=__expf(l3-mx);
    float inv = 1.0f/(e0+e1+e2+e3);
    float p0=e0*inv, p1=e1*inv, p2=e2*inv, p3=e3*inv;
    float sval = p1 + 2.f*p2 + 3.f*p3;

    constexpr int HM = (DIM==0)? HH/2 : HH;
    constexpr int WM = (DIM==0)? WW : WW/2;
    int my = (DIM==0)? (y>>1) : y;
    int mxi = (DIM==1)? (xx>>1) : xx;
    float mv = masks_in[((size_t)b*HM + my)*WM + mxi];
    masks_out[((size_t)b*HH + y)*WW + xx] = mv + 0.25f*sval;

    ent = -(p0*__logf(p0+1e-8f) + p1*__logf(p1+1e-8f) +
            p2*__logf(p2+1e-8f) + p3*__logf(p3+1e-8f));

    constexpr int FH = 256/HH, FW = 256/WW;
    float isum = 0.f;
    const float* ib = img + ((size_t)b*256 + y*FH)*256 + xx*FW;
    #pragma unroll
    for (int dy=0; dy<FH; dy++)
      #pragma unroll
      for (int dx=0; dx<FW; dx++) isum += ib[dy*256+dx];
    float img_ds = isum * (1.0f/(FH*FW));
    float d = sval*(1.0f/3.0f) - img_ds;
    mse = d*d;
  }

  #pragma unroll
  for (int off=1; off<64; off<<=1){
    ent += __shfl_xor(ent, off, 64);
    mse += __shfl_xor(mse, off, 64);
  }
  if (lane == 0){
    atomicAdd(accbuf + 2*STEP,     ent);
    atomicAdd(accbuf + 2*STEP + 1, mse);
  }
}

__global__ void finalize_kernel(const float* __restrict__ acc, float* __restrict__ out){
  const float lw[6] = {0.1f,0.1f,0.5f,0.5f,1.0f,1.0f};
  const float nn[6] = {16384.f,32768.f,65536.f,131072.f,262144.f,524288.f};
  float L=0.f;
  for (int i=0;i<6;i++) L += lw[i]*(acc[2*i]/nn[i] + acc[2*i+1]/nn[i]);
  out[0]=L;
}

extern "C" void kernel_launch(void* const* d_in, const int* in_sizes, int n_in,
                              void* d_out, int out_size, void* d_ws, size_t ws_size,
                              hipStream_t stream){
  const float* image  = (const float*)d_in[0];
  const float* w1=(const float*)d_in[2];  const float* b1=(const float*)d_in[3];
  const float* w2=(const float*)d_in[4];  const float* b2=(const float*)d_in[5];
  const float* w3=(const float*)d_in[6];  const float* b3=(const float*)d_in[7];
  const float* w4=(const float*)d_in[8];  const float* b4=(const float*)d_in[9];
  const float* upw=(const float*)d_in[10];const float* upb=(const float*)d_in[11];
  const float* mw=(const float*)d_in[12]; const float* mb=(const float*)d_in[13];
  const float* masks0=(const float*)d_in[14];
  float* out = (float*)d_out;

  char* ws = (char*)d_ws;
  size_t off = 0;
  auto alloc = [&](size_t bytes)->char*{
    char* p = ws + off; off += (bytes + 255) & ~(size_t)255; return p;
  };
  bf16* enc1  = (bf16*)alloc((size_t)8*256*256*16*2);
  bf16* enc2  = (bf16*)alloc((size_t)8*128*128*16*2);
  bf16* enc3  = (bf16*)alloc((size_t)8*64*64*32*2);
  bf16* featA = (bf16*)alloc((size_t)8*256*256*64*2);
  bf16* featB = (bf16*)alloc((size_t)8*256*128*64*2);
  float* mbA  = (float*)alloc((size_t)8*256*128*4);
  float* mbB  = (float*)alloc((size_t)8*128*128*4);
  bf16* packU = (bf16*)alloc((size_t)9*2*4*64*8*2);
  bf16* packM = (bf16*)alloc((size_t)9*2*64*8*2);
  float* acc  = (float*)alloc(256);

  hipMemsetAsync(acc, 0, 16*sizeof(float), stream);

  repack_up  <<<144,256,0,stream>>>(upw, packU);
  repack_mask<<< 36,256,0,stream>>>(mw,  packM);

  // encoder
  trio_kernel<float,1,16,1,1,256,256><<<8*256*256/256,256,0,stream>>>(image,w1,b1,enc1);
  trio_kernel<bf16,16,16,1,2,256,256><<<8*128*128/256,256,0,stream>>>(enc1,w2,b2,enc2);
  trio_kernel<bf16,16,32,2,2,128,128><<<8*64*64*2/256,256,0,stream>>>(enc2,w3,b3,enc3);
  trio_kernel<bf16,32,64,4,2,64,64><<<8*32*32*4/256,256,0,stream>>>(enc3,w4,b4,featA);

  // step 0: (32,32) -> (64,32)
  upconv_mfma<0,32,32><<<256,256,0,stream>>>(featA,packU,upb,featB);
  maskloss_mfma<0,0,64,32><<<256,256,0,stream>>>(featB,packM,mb,image,masks0,mbA,acc);
  // step 1: (64,32) -> (64,64)
  upconv_mfma<1,64,32><<<512,256,0,stream>>>(featB,packU,upb,featA);
  maskloss_mfma<1,1,64,64><<<512,256,0,stream>>>(featA,packM,mb,image,mbA,mbB,acc);
  // step 2: (64,64) -> (128,64)
  upconv_mfma<0,64,64><<<1024,256,0,stream>>>(featA,packU,upb,featB);
  maskloss_mfma<2,0,128,64><<<1024,256,0,stream>>>(featB,packM,mb,image,mbB,mbA,acc);
  // step 3: (128,64) -> (128,128)
  upconv_mfma<1,128,64><<<2048,256,0,stream>>>(featB,packU,upb,featA);
  maskloss_mfma<3,1,128,128><<<2048,256,0,stream>>>(featA,packM,mb,image,mbA,mbB,acc);
  // step 4: (128,128) -> (256,128)
  upconv_mfma<0,128,128><<<4096,256,0,stream>>>(featA,packU,upb,featB);
  maskloss_mfma<4,0,256,128><<<4096,256,0,stream>>>(featB,packM,mb,image,mbB,mbA,acc);
  // step 5: (128,128)x(256,128) -> (256,256)
  upconv_mfma<1,256,128><<<8192,256,0,stream>>>(featB,packU,upb,featA);
  maskloss_mfma<5,1,256,256><<<8192,256,0,stream>>>(featA,packM,mb,image,mbA,out+1,acc);

  finalize_kernel<<<1,1,0,stream>>>(acc,out);
}

// Round 3
// 598.241 us; speedup vs baseline: 7.0710x; 3.5590x over previous
//
#include <hip/hip_runtime.h>
#include <hip/hip_bf16.h>
#include <math.h>

typedef __hip_bfloat16 bf16;
typedef float f32x4 __attribute__((ext_vector_type(4)));
typedef __bf16 bf16x8 __attribute__((ext_vector_type(8)));

#define DEV __device__ __forceinline__

DEV float to_f(float v){ return v; }
DEV float to_f(bf16 v){ return __bfloat162float(v); }
DEV bf16 f2b(float v){ return __float2bfloat16(v); }

// tanh-approx gelu == x * sigmoid(2*0.79788456*(x+0.044715x^3)); hw exp
DEV float gelu_f(float x){
  float z = 1.5957691216057308f*(x + 0.044715f*x*x*x);
  return x / (1.0f + __expf(-z));
}

DEV bf16x8 load_frag(const bf16* p, bool ok){
  uint4 u = make_uint4(0u,0u,0u,0u);
  if (ok) u = *(const uint4*)p;
  return __builtin_bit_cast(bf16x8, u);
}

#define NSLOT 64

// ---------------- encoder Conv_trio ------------------------------------------
template<typename TIN, int CIN, int COUT, int SUB, int STRIDE, int HI, int WI>
__global__ void trio_kernel(const TIN* __restrict__ in, const float* __restrict__ w,
                            const float* __restrict__ bias, bf16* __restrict__ out){
  constexpr int HO = HI/STRIDE, WO = WI/STRIDE;
  constexpr int CO_PER = COUT/SUB;
  int gtid = blockIdx.x*blockDim.x + threadIdx.x;
  int sub = gtid % SUB;
  int pix = gtid / SUB;
  int b = pix / (HO*WO); int rem = pix % (HO*WO);
  int y = rem / WO, x = rem % WO;

  float acc[CO_PER];
  #pragma unroll
  for (int j=0;j<CO_PER;j++) acc[j]=0.f;

  for (int ky=0;ky<3;ky++){
    int iy = (STRIDE==1) ? (y+ky-1) : (2*y+ky);
    if (iy<0 || iy>=HI) continue;
    for (int kx=0;kx<3;kx++){
      int ix = (STRIDE==1) ? (x+kx-1) : (2*x+kx);
      if (ix<0 || ix>=WI) continue;
      const TIN* ip = in + ((size_t)(b*HI+iy)*WI+ix)*CIN;
      const float* wp = w + ((ky*3+kx)*CIN)*COUT + sub*CO_PER;
      #pragma unroll 4
      for (int ci=0; ci<CIN; ci++){
        float a = to_f(ip[ci]);
        const float4* w4 = (const float4*)(wp + (size_t)ci*COUT);
        #pragma unroll
        for (int j=0;j<CO_PER/4;j++){
          float4 ww = w4[j];
          acc[4*j+0] += a*ww.x; acc[4*j+1] += a*ww.y;
          acc[4*j+2] += a*ww.z; acc[4*j+3] += a*ww.w;
        }
      }
    }
  }

  float s1=0.f, s2=0.f;
  #pragma unroll
  for (int j=0;j<CO_PER;j++){
    acc[j] += bias[sub*CO_PER+j];
    s1 += acc[j]; s2 += acc[j]*acc[j];
  }
  if (SUB>=2){ s1 += __shfl_xor(s1,1,64); s2 += __shfl_xor(s2,1,64); }
  if (SUB>=4){ s1 += __shfl_xor(s1,2,64); s2 += __shfl_xor(s2,2,64); }
  float mu  = s1*(1.0f/COUT);
  float var = s2*(1.0f/COUT) - mu*mu;
  float sc  = rsqrtf(var + 1e-6f);

  bf16* op = out + (size_t)pix*COUT + sub*CO_PER;
  #pragma unroll
  for (int j=0;j<CO_PER;j++) op[j] = f2b(gelu_f((acc[j]-mu)*sc));
}

// ---------------- weight repack for MFMA B fragments ---------------------------
__global__ void repack_up(const float* __restrict__ w, bf16* __restrict__ bp){
  int v = blockIdx.x*256 + threadIdx.x;
  if (v >= 9*2*4*64*8) return;
  int j = v & 7; int lane = (v>>3)&63; int nt = (v>>9)&3; int c = (v>>11)&1; int tap = v>>12;
  int ci = c*32 + (lane>>4)*8 + j;
  int co = nt*16 + (lane&15);
  bp[v] = f2b(w[(tap*64+ci)*64 + co]);
}

__global__ void repack_mask(const float* __restrict__ w, bf16* __restrict__ bp){
  int v = blockIdx.x*256 + threadIdx.x;
  if (v >= 9*2*64*8) return;
  int j = v & 7; int lane = (v>>3)&63; int c = (v>>9)&1; int tap = v>>10;
  int ci = c*32 + (lane>>4)*8 + j;
  int n = lane & 15;
  bp[v] = (n < 4) ? f2b(w[(tap*64+ci)*4 + n]) : f2b(0.0f);
}

// ---------------- MFMA conv_transpose(3x3, stride 2 along DIM) + gelu ----------
template<int DIM, int HI, int WI>
__global__ void upconv_mfma(const bf16* __restrict__ in, const bf16* __restrict__ bpack,
                            const float* __restrict__ upb, bf16* __restrict__ out){
  constexpr int HO = (DIM==0)? HI*2 : HI;
  constexpr int WO = (DIM==0)? WI : WI*2;
  constexpr int U  = (DIM==0)? WI : HI;
  int lane = threadIdx.x & 63;
  int wv   = threadIdx.x >> 6;
  int wtile = blockIdx.x*4 + wv;
  int m = lane & 15, quad = lane >> 4;

  int b, y0=0, x0=0, o, u;
  if (DIM==0){
    constexpr int TPR = WO/16;
    x0 = (wtile % TPR)*16;
    int y = (wtile / TPR) % HO;
    b = wtile / (TPR*HO);
    y0 = y;
    o = y; u = x0 + m;
  } else {
    int x = wtile % WO;
    y0 = ((wtile / WO) % (HO/16))*16;
    b = wtile / (WO*(HO/16));
    x0 = x;
    o = x; u = y0 + m;
  }

  int q = o >> 1;
  int stk[2], stq[2]; int nst;
  if (o & 1){ stk[0]=1; stq[0]=q; nst=1; }
  else {
    nst = 0;
    if (q >= 1){ stk[0]=0; stq[0]=q-1; nst=1; }
    stk[nst]=2; stq[nst]=q; nst++;
  }

  f32x4 acc[4];
  #pragma unroll
  for (int nt=0;nt<4;nt++) acc[nt] = (f32x4){0.f,0.f,0.f,0.f};

  const uint4* bp4 = (const uint4*)bpack;

  for (int s=0; s<nst; s++){
    #pragma unroll
    for (int ut=0; ut<3; ut++){
      int uu = u - 1 + ut;
      bool ok = (uu >= 0) && (uu < U);
      int iy = (DIM==0)? stq[s] : uu;
      int ix = (DIM==0)? uu : stq[s];
      int tap = (DIM==0)? stk[s]*3+ut : ut*3+stk[s];
      const bf16* ip = in + (((size_t)(b*HI+iy)*WI + ix)*64 + quad*8);
      #pragma unroll
      for (int c=0;c<2;c++){
        bf16x8 a = load_frag(ip + c*32, ok);
        #pragma unroll
        for (int nt=0;nt<4;nt++){
          uint4 ub = bp4[((tap*2+c)*4+nt)*64 + lane];
          bf16x8 bb = __builtin_bit_cast(bf16x8, ub);
          acc[nt] = __builtin_amdgcn_mfma_f32_16x16x32_bf16(a, bb, acc[nt], 0, 0, 0);
        }
      }
    }
  }

  int col = m;
  #pragma unroll
  for (int nt=0;nt<4;nt++){
    float bv = upb[nt*16 + col];
    #pragma unroll
    for (int r=0;r<4;r++){
      int p = quad*4 + r;
      size_t opix = (DIM==0) ? (((size_t)b*HO + y0)*WO + x0 + p)
                             : (((size_t)b*HO + y0 + p)*WO + x0);
      out[opix*64 + nt*16 + col] = f2b(gelu_f(acc[nt][r] + bv));
    }
  }
}

// ---------------- MFMA mask conv + softmax + mask update + loss ----------------
// One wave computes TILES*16 consecutive pixels in row y; all lanes active in
// epilogue; block-level LDS reduction -> 1 atomic pair per block, spread slots.
template<int STEP, int DIM, int HH, int WW, int TILES>
__global__ void maskloss_mfma(const bf16* __restrict__ feat, const bf16* __restrict__ mpack,
                              const float* __restrict__ mb, const float* __restrict__ img,
                              const float* __restrict__ masks_in, float* __restrict__ masks_out,
                              float* __restrict__ accbuf){
  __shared__ float llog[4][64][4];
  __shared__ float red[4][2];
  int lane = threadIdx.x & 63;
  int wv   = threadIdx.x >> 6;
  int wtile = blockIdx.x*4 + wv;
  int m = lane & 15, quad = lane >> 4;

  constexpr int TPR = WW/(16*TILES);
  int x0 = (wtile % TPR)*(16*TILES);
  int y  = (wtile / TPR) % HH;
  int b  = wtile / (TPR*HH);

  const uint4* bp4 = (const uint4*)mpack;
  uint4 barr[9][2];
  #pragma unroll
  for (int tap=0; tap<9; tap++)
    #pragma unroll
    for (int c=0;c<2;c++)
      barr[tap][c] = bp4[(tap*2+c)*64 + lane];

  #pragma unroll
  for (int t=0; t<TILES; t++){
    f32x4 acc4 = (f32x4){0.f,0.f,0.f,0.f};
    for (int ky=0; ky<3; ky++){
      int iy = y + ky - 1;
      if (iy < 0 || iy >= HH) continue;
      #pragma unroll
      for (int kx=0; kx<3; kx++){
        int ix = x0 + t*16 + m + kx - 1;
        bool ok = (ix >= 0) && (ix < WW);
        const bf16* ip = feat + (((size_t)(b*HH+iy)*WW + ix)*64 + quad*8);
        #pragma unroll
        for (int c=0;c<2;c++){
          bf16x8 a = load_frag(ip + c*32, ok);
          bf16x8 bb = __builtin_bit_cast(bf16x8, barr[ky*3+kx][c]);
          acc4 = __builtin_amdgcn_mfma_f32_16x16x32_bf16(a, bb, acc4, 0, 0, 0);
        }
      }
    }
    if (m < 4){
      #pragma unroll
      for (int r=0;r<4;r++) llog[wv][t*16 + quad*4 + r][m] = acc4[r] + mb[m];
    }
  }
  __syncthreads();

  float ent = 0.f, mse = 0.f;
  if (lane < 16*TILES){
    int p = lane; int xx = x0 + p;
    float l0 = llog[wv][p][0], l1 = llog[wv][p][1];
    float l2 = llog[wv][p][2], l3 = llog[wv][p][3];
    float mx = fmaxf(fmaxf(l0,l1), fmaxf(l2,l3));
    float e0=__expf(l0-mx), e1=__expf(l1-mx), e2=__expf(l2-mx), e3=__expf(l3-mx);
    float inv = 1.0f/(e0+e1+e2+e3);
    float p0=e0*inv, p1=e1*inv, p2=e2*inv, p3=e3*inv;
    float sval = p1 + 2.f*p2 + 3.f*p3;

    constexpr int HM = (DIM==0)? HH/2 : HH;
    constexpr int WM = (DIM==0)? WW : WW/2;
    int my = (DIM==0)? (y>>1) : y;
    int mxi = (DIM==1)? (xx>>1) : xx;
    float mv = masks_in[((size_t)b*HM + my)*WM + mxi];
    masks_out[((size_t)b*HH + y)*WW + xx] = mv + 0.25f*sval;

    ent = -(p0*__logf(p0+1e-8f) + p1*__logf(p1+1e-8f) +
            p2*__logf(p2+1e-8f) + p3*__logf(p3+1e-8f));

    constexpr int FH = 256/HH, FW = 256/WW;
    float isum = 0.f;
    const float* ib = img + ((size_t)b*256 + y*FH)*256 + xx*FW;
    #pragma unroll
    for (int dy=0; dy<FH; dy++)
      #pragma unroll
      for (int dx=0; dx<FW; dx++) isum += ib[dy*256+dx];
    float img_ds = isum * (1.0f/(FH*FW));
    float d = sval*(1.0f/3.0f) - img_ds;
    mse = d*d;
  }

  #pragma unroll
  for (int off=1; off<64; off<<=1){
    ent += __shfl_xor(ent, off, 64);
    mse += __shfl_xor(mse, off, 64);
  }
  if (lane == 0){ red[wv][0] = ent; red[wv][1] = mse; }
  __syncthreads();
  if (threadIdx.x == 0){
    float e  = red[0][0] + red[1][0] + red[2][0] + red[3][0];
    float ms = red[0][1] + red[1][1] + red[2][1] + red[3][1];
    int slot = blockIdx.x & (NSLOT-1);
    atomicAdd(accbuf + (2*STEP  )*NSLOT + slot, e);
    atomicAdd(accbuf + (2*STEP+1)*NSLOT + slot, ms);
  }
}

__global__ void finalize_kernel(const float* __restrict__ acc, float* __restrict__ out){
  int lane = threadIdx.x & 63;
  float v[12];
  #pragma unroll
  for (int i=0;i<12;i++){
    float x = acc[i*NSLOT + lane];
    #pragma unroll
    for (int off=1; off<64; off<<=1) x += __shfl_xor(x, off, 64);
    v[i] = x;
  }
  if (lane == 0){
    const float lw[6] = {0.1f,0.1f,0.5f,0.5f,1.0f,1.0f};
    const float nn[6] = {16384.f,32768.f,65536.f,131072.f,262144.f,524288.f};
    float L=0.f;
    for (int i=0;i<6;i++) L += lw[i]*((v[2*i] + v[2*i+1])/nn[i]);
    out[0]=L;
  }
}

extern "C" void kernel_launch(void* const* d_in, const int* in_sizes, int n_in,
                              void* d_out, int out_size, void* d_ws, size_t ws_size,
                              hipStream_t stream){
  const float* image  = (const float*)d_in[0];
  const float* w1=(const float*)d_in[2];  const float* b1=(const float*)d_in[3];
  const float* w2=(const float*)d_in[4];  const float* b2=(const float*)d_in[5];
  const float* w3=(const float*)d_in[6];  const float* b3=(const float*)d_in[7];
  const float* w4=(const float*)d_in[8];  const float* b4=(const float*)d_in[9];
  const float* upw=(const float*)d_in[10];const float* upb=(const float*)d_in[11];
  const float* mw=(const float*)d_in[12]; const float* mb=(const float*)d_in[13];
  const float* masks0=(const float*)d_in[14];
  float* out = (float*)d_out;

  char* ws = (char*)d_ws;
  size_t off = 0;
  auto alloc = [&](size_t bytes)->char*{
    char* p = ws + off; off += (bytes + 255) & ~(size_t)255; return p;
  };
  bf16* enc1  = (bf16*)alloc((size_t)8*256*256*16*2);
  bf16* enc2  = (bf16*)alloc((size_t)8*128*128*16*2);
  bf16* enc3  = (bf16*)alloc((size_t)8*64*64*32*2);
  bf16* featA = (bf16*)alloc((size_t)8*256*256*64*2);
  bf16* featB = (bf16*)alloc((size_t)8*256*128*64*2);
  float* mbA  = (float*)alloc((size_t)8*256*128*4);
  float* mbB  = (float*)alloc((size_t)8*128*128*4);
  bf16* packU = (bf16*)alloc((size_t)9*2*4*64*8*2);
  bf16* packM = (bf16*)alloc((size_t)9*2*64*8*2);
  float* acc  = (float*)alloc(12*NSLOT*sizeof(float));

  hipMemsetAsync(acc, 0, 12*NSLOT*sizeof(float), stream);

  repack_up  <<<144,256,0,stream>>>(upw, packU);
  repack_mask<<< 36,256,0,stream>>>(mw,  packM);

  // encoder
  trio_kernel<float,1,16,1,1,256,256><<<8*256*256/256,256,0,stream>>>(image,w1,b1,enc1);
  trio_kernel<bf16,16,16,1,2,256,256><<<8*128*128/256,256,0,stream>>>(enc1,w2,b2,enc2);
  trio_kernel<bf16,16,32,2,2,128,128><<<8*64*64*2/256,256,0,stream>>>(enc2,w3,b3,enc3);
  trio_kernel<bf16,32,64,4,2,64,64><<<8*32*32*4/256,256,0,stream>>>(enc3,w4,b4,featA);

  // step 0: (32,32) -> (64,32)
  upconv_mfma<0,32,32><<<256,256,0,stream>>>(featA,packU,upb,featB);
  maskloss_mfma<0,0,64,32,2><<<128,256,0,stream>>>(featB,packM,mb,image,masks0,mbA,acc);
  // step 1: (64,32) -> (64,64)
  upconv_mfma<1,64,32><<<512,256,0,stream>>>(featB,packU,upb,featA);
  maskloss_mfma<1,1,64,64,4><<<128,256,0,stream>>>(featA,packM,mb,image,mbA,mbB,acc);
  // step 2: (64,64) -> (128,64)
  upconv_mfma<0,64,64><<<1024,256,0,stream>>>(featA,packU,upb,featB);
  maskloss_mfma<2,0,128,64,4><<<256,256,0,stream>>>(featB,packM,mb,image,mbB,mbA,acc);
  // step 3: (128,64) -> (128,128)
  upconv_mfma<1,128,64><<<2048,256,0,stream>>>(featB,packU,upb,featA);
  maskloss_mfma<3,1,128,128,4><<<512,256,0,stream>>>(featA,packM,mb,image,mbA,mbB,acc);
  // step 4: (128,128) -> (256,128)
  upconv_mfma<0,128,128><<<4096,256,0,stream>>>(featA,packU,upb,featB);
  maskloss_mfma<4,0,256,128,4><<<1024,256,0,stream>>>(featB,packM,mb,image,mbB,mbA,acc);
  // step 5: (128,128)x(256,128) -> (256,256)
  upconv_mfma<1,256,128><<<8192,256,0,stream>>>(featB,packU,upb,featA);
  maskloss_mfma<5,1,256,256,4><<<2048,256,0,stream>>>(featA,packM,mb,image,mbA,out+1,acc);

  finalize_kernel<<<1,64,0,stream>>>(acc,out);
}